// Round 10
// baseline (167.098 us; speedup 1.0000x reference)
//
#include <hip/hip_runtime.h>
#include <stdint.h>

#define L_SEQ 4096
#define D_MODEL 1024
#define HEAD 64
#define KCH 256         // kv per chunk (4 stages of 64)
#define MAXCH 16
#define NQT 32          // 128-row q tiles

typedef unsigned short u16;
typedef _Float16 f16;
typedef __attribute__((ext_vector_type(8))) f16 f16x8;
typedef __attribute__((ext_vector_type(2))) __fp16 fp16x2;
typedef __attribute__((ext_vector_type(4))) float f32x4;

static __device__ __forceinline__ u16 f16bits(float f) {
    union { f16 h; u16 u; } c; c.h = (f16)f; return c.u;
}
static __device__ __forceinline__ uint32_t pk16(float a, float b) {
    union { fp16x2 h; uint32_t u; } c;
    c.h = __builtin_amdgcn_cvt_pkrtz(a, b);
    return c.u;
}
static __device__ __forceinline__ f16x8 ld8h(const u16* p) { return *(const f16x8*)p; }

static __device__ __forceinline__ f32x4 mfma16h(f16x8 a, f16x8 b, f32x4 c) {
    return __builtin_amdgcn_mfma_f32_16x16x32_f16(a, b, c, 0, 0, 0);
}

// async global->LDS, 16B per lane, fire-and-forget (cannot be sunk)
static __device__ __forceinline__ void gload16(const u16* g, u16* l) {
    __builtin_amdgcn_global_load_lds(
        (const __attribute__((address_space(1))) void*)g,
        (__attribute__((address_space(3))) void*)l, 16, 0, 0);
}

// prefix of compacted (qt,ch) slots: S(qt) = sum_{k<qt} ceil((k+1)/2)
static __device__ __forceinline__ int Sq(int qt) {
    return (qt & 1) ? ((qt + 1) * (qt + 1)) >> 2 : (qt * (qt + 2)) >> 2;
}

// --- Kernel 0: W fp32 [1024,64] -> f16 Wt [64,1024] x3; Wq scaled log2e/8
__global__ __launch_bounds__(256) void conv_w(
    const float* __restrict__ Wq, const float* __restrict__ Wk,
    const float* __restrict__ Wv, u16* __restrict__ Wt)
{
    __shared__ u16 tile[64][72];
    const float* W = (blockIdx.y == 0) ? Wq : (blockIdx.y == 1) ? Wk : Wv;
    const float sc = (blockIdx.y == 0) ? 0.18033688f : 1.0f;  // log2(e)/8
    u16* dst = Wt + blockIdx.y * (HEAD * D_MODEL);
    const int k0 = blockIdx.x * 64, t = threadIdx.x;
    #pragma unroll
    for (int i = 0; i < 16; i++) {
        int idx = i * 256 + t;
        int kk = idx >> 6, h = idx & 63;
        tile[h][kk] = f16bits(W[(size_t)(k0 + kk) * HEAD + h] * sc);
    }
    __syncthreads();
    #pragma unroll
    for (int i = 0; i < 16; i++) {
        int idx = i * 256 + t;
        int h = idx >> 6, kk = idx & 63;
        dst[(size_t)h * D_MODEL + k0 + kk] = tile[h][kk];
    }
}

// --- Kernel 1: QKV projection, dbuf LDS GEMM; reads-before-issue ordering.
__global__ __launch_bounds__(256) void qkv_proj(
    const float* __restrict__ x, const u16* __restrict__ Wt,
    u16* __restrict__ qb, u16* __restrict__ kb, u16* __restrict__ vTb)
{
    __shared__ __align__(16) u16 Wl[2 * 2 * 192 * 32];   // 49152 B
    __shared__ __align__(16) u16 Xl[2 * 2 * 32 * 36];    // 9216 B
#define WLX(bb,dh,r,c) Wl[(((bb)*2 + (dh))*192 + (r))*32 + (c)]
#define XLX(bb,kh,r,c) Xl[(((bb)*2 + (kh))*32  + (r))*36 + (c)]
#define CT(r,c)        ((u16*)Wl)[(r)*200 + (c)]        // epilogue overlay

    const int t = threadIdx.x;
    const int wv = t >> 6, lane = t & 63;
    const int ln16 = lane & 15, quad = lane >> 4;
    const int w3 = wv * 3;
    const int m0 = blockIdx.x * 32;

    f32x4 acc[2][3] = {};
    float4 xv0, xv1;

    auto issueW = [&](int s, int bb) {
        const int k0 = s * 64;
        #pragma unroll
        for (int k2 = 0; k2 < 6; k2++) {
            int c = wv * 6 + k2;
            int dh = c & 1, g = c >> 1;
            const u16* gp = Wt + (size_t)(g * 16 + (lane >> 2)) * D_MODEL
                               + k0 + dh * 32 + (lane & 3) * 8;
            gload16(gp, &WLX(bb, dh, g * 16 + (lane >> 2), (lane & 3) * 8));
        }
    };
    auto loadx = [&](int s) {
        const int k0 = s * 64;
        int r0 = t >> 4, cs0 = (t & 15) * 4;
        xv0 = *(const float4*)&x[(size_t)(m0 + r0) * D_MODEL + k0 + cs0];
        int idx = 256 + t, r1 = idx >> 4, cs1 = (idx & 15) * 4;
        xv1 = *(const float4*)&x[(size_t)(m0 + r1) * D_MODEL + k0 + cs1];
    };
    auto packx = [&](int bb) {
        int r0 = t >> 4, cs0 = (t & 15) * 4;
        uint2 p0; p0.x = pk16(xv0.x, xv0.y); p0.y = pk16(xv0.z, xv0.w);
        *(uint2*)&XLX(bb, cs0 >> 5, r0, cs0 & 31) = p0;
        int idx = 256 + t, r1 = idx >> 4, cs1 = (idx & 15) * 4;
        uint2 p1; p1.x = pk16(xv1.x, xv1.y); p1.y = pk16(xv1.z, xv1.w);
        *(uint2*)&XLX(bb, cs1 >> 5, r1, cs1 & 31) = p1;
    };

    loadx(0); issueW(0, 0); packx(0);
    int buf = 0;
    for (int s = 0; s < 16; s++) {
        __syncthreads();
        // 1) read all frags from current buffer (no outstanding vmem -> no waits)
        f16x8 xb[2][2], af[2][3];
        #pragma unroll
        for (int c = 0; c < 2; c++) {
            xb[c][0] = ld8h(&XLX(buf, c, ln16, quad * 8));
            xb[c][1] = ld8h(&XLX(buf, c, 16 + ln16, quad * 8));
            #pragma unroll
            for (int j = 0; j < 3; j++)
                af[c][j] = ld8h(&WLX(buf, c, (w3 + j) * 16 + ln16, quad * 8));
        }
        // 2) issue next stage (x regs first so packx won't wait on W gloads)
        if (s + 1 < 16) { loadx(s + 1); issueW(s + 1, buf ^ 1); }
        // 3) compute on registers
        #pragma unroll
        for (int c = 0; c < 2; c++)
            #pragma unroll
            for (int j = 0; j < 3; j++) {
                acc[0][j] = mfma16h(af[c][j], xb[c][0], acc[0][j]);
                acc[1][j] = mfma16h(af[c][j], xb[c][1], acc[1][j]);
            }
        if (s + 1 < 16) packx(buf ^ 1);
        buf ^= 1;
    }

    __syncthreads();   // staging done; overlay Ct on W region
    #pragma unroll
    for (int mt = 0; mt < 2; mt++) {
        #pragma unroll
        for (int j = 0; j < 3; j++) {
            int g0 = (w3 + j) * 16 + quad * 4;
            uint2 pk;
            pk.x = pk16(acc[mt][j][0], acc[mt][j][1]);
            pk.y = pk16(acc[mt][j][2], acc[mt][j][3]);
            *(uint2*)&CT(mt * 16 + ln16, g0) = pk;
        }
    }
    __syncthreads();
    {
        int m = t >> 3, hg = (t & 7) * 8;
        *(f16x8*)&qb[(size_t)(m0 + m) * HEAD + hg] = *(f16x8*)&CT(m, hg);
        *(f16x8*)&kb[(size_t)(m0 + m) * HEAD + hg] = *(f16x8*)&CT(m, 64 + hg);
        int h = t >> 2, mg = (t & 3) * 8;
        f16x8 vvv;
        #pragma unroll
        for (int jj = 0; jj < 8; jj++)
            ((u16*)&vvv)[jj] = CT(mg + jj, 128 + h);
        int bbt = m0 >> 12, l0 = m0 & 4095;
        *(f16x8*)&vTb[(size_t)(bbt * HEAD + h) * L_SEQ + l0 + mg] = vvv;
    }
#undef WLX
#undef XLX
#undef CT
}

// --- Kernel 2: split-KV causal attention. Uniform 256-kv chunks (<=4 stages),
// single-buffered async staging, 34 KB LDS -> 4 blocks/CU, exp2 softmax.
__global__ __launch_bounds__(256, 4) void attn_chunk(
    const u16* __restrict__ qb, const u16* __restrict__ kb,
    const u16* __restrict__ vT, float* __restrict__ Opart, float* __restrict__ lpart)
{
    const int qt = blockIdx.x, ch = blockIdx.y, b = blockIdx.z;
    if (ch * KCH > qt * 128 + 127) return;

    __shared__ __align__(16) u16 Kls[2 * 64 * 32];   // 8 KB  [dh][64][32]
    __shared__ __align__(16) u16 Vls[2 * 64 * 32];   // 8 KB  [kh][64][32]
    __shared__ __align__(16) u16 Pls[4 * 32 * 72];   // 18 KB wave-private P
#define KBX(dh,r,c) Kls[((dh)*64 + (r))*32 + (c)]
#define VBX(kh,r,c) Vls[((kh)*64 + (r))*32 + (c)]
#define PX(r,c)     Pls[((wv)*32 + (r))*72 + (c)]

    const int t = threadIdx.x, wv = t >> 6, lane = t & 63;
    const int ln16 = lane & 15, quad = lane >> 4;
    const int qmin = qt * 128 + wv * 32;

    // Q as B-operand: B[k=d=quad*8+j][n=q=ln16]; q pre-scaled log2e/8 via Wq
    f16x8 qf[2][2];
    #pragma unroll
    for (int qn = 0; qn < 2; qn++) {
        const u16* qrp = qb + (size_t)(b * L_SEQ + qmin + qn * 16 + ln16) * HEAD + quad * 8;
        qf[qn][0] = ld8h(qrp); qf[qn][1] = ld8h(qrp + 32);
    }

    const u16* kbb = kb + (size_t)b * L_SEQ * HEAD;
    const u16* vbb = vT + (size_t)b * HEAD * L_SEQ;

    f32x4 o[2][4] = {};            // O^T[h=hg*16+quad*4+r][q=qn*16+ln16]
    float lsum[2] = {0.f, 0.f};

    const int kv_lo = ch * KCH;
    const int kv_hi = min(kv_lo + KCH, qt * 128 + 128);
    const int nst = (kv_hi - kv_lo) >> 6;

    auto issue_stage = [&](int kv0) {
        #pragma unroll
        for (int k2 = 0; k2 < 4; k2++) {
            int c = wv * 4 + k2;
            if (c < 8) {
                int dh = c & 1, g = c >> 1;
                const u16* gp = kbb + (size_t)(kv0 + g * 16 + (lane >> 2)) * HEAD
                                    + dh * 32 + (lane & 3) * 8;
                gload16(gp, &KBX(dh, g * 16 + (lane >> 2), (lane & 3) * 8));
            } else {
                int c2 = c - 8, kh = c2 & 1, g = c2 >> 1;
                const u16* gp = vbb + (size_t)(g * 16 + (lane >> 2)) * L_SEQ
                                    + kv0 + kh * 32 + (lane & 3) * 8;
                gload16(gp, &VBX(kh, g * 16 + (lane >> 2), (lane & 3) * 8));
            }
        }
    };

    for (int s = 0; s < nst; s++) {
        const int kv0 = kv_lo + s * 64;
        issue_stage(kv0);
        __syncthreads();               // drain staging (vmcnt0 + sync)

        #pragma unroll
        for (int g = 0; g < 4; g++) {
            f16x8 ka0 = ld8h(&KBX(0, g * 16 + ln16, quad * 8));
            f16x8 ka1 = ld8h(&KBX(1, g * 16 + ln16, quad * 8));
            #pragma unroll
            for (int qn = 0; qn < 2; qn++) {
                f32x4 s2 = {};
                s2 = mfma16h(ka0, qf[qn][0], s2);
                s2 = mfma16h(ka1, qf[qn][1], s2);
                // S^T[kv=kv0+g*16+quad*4+r][q=qmin+qn*16+ln16]; p = 2^s
                float p0, p1, p2, p3;
                if (kv0 + g * 16 + 15 <= qmin + qn * 16) {     // fully unmasked
                    p0 = __builtin_amdgcn_exp2f(s2[0]);
                    p1 = __builtin_amdgcn_exp2f(s2[1]);
                    p2 = __builtin_amdgcn_exp2f(s2[2]);
                    p3 = __builtin_amdgcn_exp2f(s2[3]);
                } else {
                    int q = qmin + qn * 16 + ln16;
                    int kv = kv0 + g * 16 + quad * 4;
                    p0 = (kv     <= q) ? __builtin_amdgcn_exp2f(s2[0]) : 0.f;
                    p1 = (kv + 1 <= q) ? __builtin_amdgcn_exp2f(s2[1]) : 0.f;
                    p2 = (kv + 2 <= q) ? __builtin_amdgcn_exp2f(s2[2]) : 0.f;
                    p3 = (kv + 3 <= q) ? __builtin_amdgcn_exp2f(s2[3]) : 0.f;
                }
                lsum[qn] += (p0 + p1) + (p2 + p3);
                uint2 pk; pk.x = pk16(p0, p1); pk.y = pk16(p2, p3);
                *(uint2*)&PX(qn * 16 + ln16, g * 16 + quad * 4) = pk;
            }
        }
        // P back as B-operand (same-wave LDS, ordered)
        f16x8 pf[2][2];
        #pragma unroll
        for (int qn = 0; qn < 2; qn++) {
            pf[qn][0] = ld8h(&PX(qn * 16 + ln16, quad * 8));
            pf[qn][1] = ld8h(&PX(qn * 16 + ln16, 32 + quad * 8));
        }
        #pragma unroll
        for (int hg = 0; hg < 4; hg++) {
            f16x8 va0 = ld8h(&VBX(0, hg * 16 + ln16, quad * 8));
            f16x8 va1 = ld8h(&VBX(1, hg * 16 + ln16, quad * 8));
            #pragma unroll
            for (int qn = 0; qn < 2; qn++) {
                o[qn][hg] = mfma16h(va0, pf[qn][0], o[qn][hg]);
                o[qn][hg] = mfma16h(va1, pf[qn][1], o[qn][hg]);
            }
        }
        __syncthreads();               // LDS reads done before next overwrite
    }

    #pragma unroll
    for (int qn = 0; qn < 2; qn++) {
        lsum[qn] += __shfl_xor(lsum[qn], 16);
        lsum[qn] += __shfl_xor(lsum[qn], 32);
    }

    const size_t base = (size_t)(b * 272 + Sq(qt) + ch);
    #pragma unroll
    for (int qn = 0; qn < 2; qn++) {
        int q_local = wv * 32 + qn * 16 + ln16;
        #pragma unroll
        for (int hg = 0; hg < 4; hg++)
            *(f32x4*)&Opart[base * 8192 + (size_t)q_local * 64 + hg * 16 + quad * 4] = o[qn][hg];
        if (quad == 0)
            lpart[base * 128 + q_local] = lsum[qn];
    }
#undef KBX
#undef VBX
#undef PX
}

// --- Kernel 3: merge partials; <=16 chunks, scalar-branch-guarded loads.
__global__ __launch_bounds__(256) void merge_chunks(
    const float* __restrict__ Opart, const float* __restrict__ lpart,
    float* __restrict__ out)
{
    const int qt = blockIdx.x, qseg = blockIdx.y, b = blockIdx.z;
    const int nch = (qt + 2) >> 1;
    const int t = threadIdx.x;
    const size_t obase = (size_t)(b * 272 + Sq(qt)) * 8192;
    const size_t lbase = (size_t)(b * 272 + Sq(qt)) * 128;
    #pragma unroll
    for (int i = 0; i < 2; i++) {
        int idx = i * 256 + t;              // 32 q x 16 h-groups
        int q = qseg * 32 + (idx >> 4), hg = (idx & 15) * 4;
        float L = 0.f, ax = 0.f, ay = 0.f, az = 0.f, aw = 0.f;
        #pragma unroll
        for (int c = 0; c < MAXCH; c++) {
            if (c < nch) {                  // block-uniform scalar branch
                L += lpart[lbase + c * 128 + q];
                const float4 v = *(const float4*)&Opart[obase + (size_t)c * 8192 + q * 64 + hg];
                ax += v.x; ay += v.y; az += v.z; aw += v.w;
            }
        }
        float inv = 1.f / L;
        float4 r; r.x = ax * inv; r.y = ay * inv; r.z = az * inv; r.w = aw * inv;
        *(float4*)&out[((size_t)(b * L_SEQ + qt * 128 + q)) * HEAD + hg] = r;
    }
}

extern "C" void kernel_launch(void* const* d_in, const int* in_sizes, int n_in,
                              void* d_out, int out_size, void* d_ws, size_t ws_size,
                              hipStream_t stream) {
    const float* x  = (const float*)d_in[0];
    const float* Wq = (const float*)d_in[1];
    const float* Wk = (const float*)d_in[2];
    const float* Wv = (const float*)d_in[3];
    float* out = (float*)d_out;

    u16* ws16 = (u16*)d_ws;
    u16* Wt  = ws16;                          // [192][1024] f16 (q|k|v rows)
    u16* qb  = Wt + 3 * HEAD * D_MODEL;       // [4,4096,64] f16
    u16* kb  = qb + 16384 * HEAD;
    u16* vTb = kb + 16384 * HEAD;             // [4,64,4096] f16
    float* Opart = (float*)(vTb + 16384 * HEAD);   // [4*272][8192] f32 = 35.7 MB
    float* lpart = Opart + (size_t)4 * 272 * 8192; // [4*272][128] f32

    conv_w      <<<dim3(16, 3), 256, 0, stream>>>(Wq, Wk, Wv, Wt);
    qkv_proj    <<<dim3(512), 256, 0, stream>>>(x, Wt, qb, kb, vTb);
    attn_chunk  <<<dim3(NQT, MAXCH, 4), 256, 0, stream>>>(qb, kb, vTb, Opart, lpart);
    merge_chunks<<<dim3(NQT, 4, 4), 256, 0, stream>>>(Opart, lpart, out);
}

// Round 11
// 152.687 us; speedup vs baseline: 1.0944x; 1.0944x over previous
//
#include <hip/hip_runtime.h>
#include <stdint.h>

#define L_SEQ 4096
#define D_MODEL 1024
#define HEAD 64
#define KCH 512         // kv per chunk (<=8 stages of 64)
#define MAXCH 8
#define NQT 32          // 128-row q tiles

typedef unsigned short u16;
typedef _Float16 f16;
typedef __attribute__((ext_vector_type(8))) f16 f16x8;
typedef __attribute__((ext_vector_type(2))) __fp16 fp16x2;
typedef __attribute__((ext_vector_type(4))) float f32x4;

static __device__ __forceinline__ u16 f16bits(float f) {
    union { f16 h; u16 u; } c; c.h = (f16)f; return c.u;
}
static __device__ __forceinline__ uint32_t pk16(float a, float b) {
    union { fp16x2 h; uint32_t u; } c;
    c.h = __builtin_amdgcn_cvt_pkrtz(a, b);
    return c.u;
}
static __device__ __forceinline__ f16x8 ld8h(const u16* p) { return *(const f16x8*)p; }

static __device__ __forceinline__ f32x4 mfma16h(f16x8 a, f16x8 b, f32x4 c) {
    return __builtin_amdgcn_mfma_f32_16x16x32_f16(a, b, c, 0, 0, 0);
}

// async global->LDS, 16B per lane, fire-and-forget (cannot be sunk)
static __device__ __forceinline__ void gload16(const u16* g, u16* l) {
    __builtin_amdgcn_global_load_lds(
        (const __attribute__((address_space(1))) void*)g,
        (__attribute__((address_space(3))) void*)l, 16, 0, 0);
}

// compacted slot prefix: Sq(qt) = sum_{k<qt} ceil((k+1)/4); total Sq(32)=144
static __device__ __forceinline__ int Sq(int qt) {
    int f = qt >> 2, r = qt & 3;
    return (f + 1) * (2 * f + r);
}

// --- Kernel 0: W fp32 [1024,64] -> f16 Wt [64,1024] x3; Wq scaled log2e/8
__global__ __launch_bounds__(256) void conv_w(
    const float* __restrict__ Wq, const float* __restrict__ Wk,
    const float* __restrict__ Wv, u16* __restrict__ Wt)
{
    __shared__ u16 tile[64][72];
    const float* W = (blockIdx.y == 0) ? Wq : (blockIdx.y == 1) ? Wk : Wv;
    const float sc = (blockIdx.y == 0) ? 0.18033688f : 1.0f;  // log2(e)/8
    u16* dst = Wt + blockIdx.y * (HEAD * D_MODEL);
    const int k0 = blockIdx.x * 64, t = threadIdx.x;
    #pragma unroll
    for (int i = 0; i < 16; i++) {
        int idx = i * 256 + t;
        int kk = idx >> 6, h = idx & 63;
        tile[h][kk] = f16bits(W[(size_t)(k0 + kk) * HEAD + h] * sc);
    }
    __syncthreads();
    #pragma unroll
    for (int i = 0; i < 16; i++) {
        int idx = i * 256 + t;
        int h = idx >> 6, kk = idx & 63;
        dst[(size_t)h * D_MODEL + k0 + kk] = tile[h][kk];
    }
}

// --- Kernel 1: QKV projection, SINGLE-buffered LDS GEMM, 29 KB -> 4 blk/CU.
// Barrier drains everything per stage anyway -> trade dbuf ILP for TLP.
__global__ __launch_bounds__(256, 4) void qkv_proj(
    const float* __restrict__ x, const u16* __restrict__ Wt,
    u16* __restrict__ qb, u16* __restrict__ kb, u16* __restrict__ vTb)
{
    __shared__ __align__(16) u16 Wl[2 * 192 * 32];   // 24576 B [dh][192][32]
    __shared__ __align__(16) u16 Xl[2 * 32 * 36];    // 4608 B  [kh][32][36]
#define WLX(dh,r,c) Wl[((dh)*192 + (r))*32 + (c)]
#define XLX(kh,r,c) Xl[((kh)*32  + (r))*36 + (c)]
#define CT(r,c)     Wl[(r)*200 + (c)]               // epilogue overlay

    const int t = threadIdx.x;
    const int wv = t >> 6, lane = t & 63;
    const int ln16 = lane & 15, quad = lane >> 4;
    const int w3 = wv * 3;
    const int m0 = blockIdx.x * 32;

    f32x4 acc[2][3] = {};
    float4 xv0, xv1;

    auto issueW = [&](int s) {
        const int k0 = s * 64;
        #pragma unroll
        for (int k2 = 0; k2 < 6; k2++) {
            int c = wv * 6 + k2;
            int dh = c & 1, g = c >> 1;
            const u16* gp = Wt + (size_t)(g * 16 + (lane >> 2)) * D_MODEL
                               + k0 + dh * 32 + (lane & 3) * 8;
            gload16(gp, &WLX(dh, g * 16 + (lane >> 2), (lane & 3) * 8));
        }
    };
    auto loadx = [&](int s) {
        const int k0 = s * 64;
        int r0 = t >> 4, cs0 = (t & 15) * 4;
        xv0 = *(const float4*)&x[(size_t)(m0 + r0) * D_MODEL + k0 + cs0];
        int idx = 256 + t, r1 = idx >> 4, cs1 = (idx & 15) * 4;
        xv1 = *(const float4*)&x[(size_t)(m0 + r1) * D_MODEL + k0 + cs1];
    };
    auto packx = [&]() {
        int r0 = t >> 4, cs0 = (t & 15) * 4;
        uint2 p0; p0.x = pk16(xv0.x, xv0.y); p0.y = pk16(xv0.z, xv0.w);
        *(uint2*)&XLX(cs0 >> 5, r0, cs0 & 31) = p0;
        int idx = 256 + t, r1 = idx >> 4, cs1 = (idx & 15) * 4;
        uint2 p1; p1.x = pk16(xv1.x, xv1.y); p1.y = pk16(xv1.z, xv1.w);
        *(uint2*)&XLX(cs1 >> 5, r1, cs1 & 31) = p1;
    };

    loadx(0); issueW(0); packx();
    for (int s = 0; s < 16; s++) {
        __syncthreads();          // drains W gloads + x LDS writes of stage s
        f16x8 xb[2][2], af[2][3];
        #pragma unroll
        for (int c = 0; c < 2; c++) {
            xb[c][0] = ld8h(&XLX(c, ln16, quad * 8));
            xb[c][1] = ld8h(&XLX(c, 16 + ln16, quad * 8));
            #pragma unroll
            for (int j = 0; j < 3; j++)
                af[c][j] = ld8h(&WLX(c, (w3 + j) * 16 + ln16, quad * 8));
        }
        #pragma unroll
        for (int c = 0; c < 2; c++)
            #pragma unroll
            for (int j = 0; j < 3; j++) {
                acc[0][j] = mfma16h(af[c][j], xb[c][0], acc[0][j]);
                acc[1][j] = mfma16h(af[c][j], xb[c][1], acc[1][j]);
            }
        if (s + 1 < 16) loadx(s + 1);   // x latency hidden by barrier below
        __syncthreads();          // all LDS reads of stage s complete
        if (s + 1 < 16) { issueW(s + 1); packx(); }
    }

    __syncthreads();   // overlay Ct on W region
    #pragma unroll
    for (int mt = 0; mt < 2; mt++) {
        #pragma unroll
        for (int j = 0; j < 3; j++) {
            int g0 = (w3 + j) * 16 + quad * 4;
            uint2 pk;
            pk.x = pk16(acc[mt][j][0], acc[mt][j][1]);
            pk.y = pk16(acc[mt][j][2], acc[mt][j][3]);
            *(uint2*)&CT(mt * 16 + ln16, g0) = pk;
        }
    }
    __syncthreads();
    {
        int m = t >> 3, hg = (t & 7) * 8;
        *(f16x8*)&qb[(size_t)(m0 + m) * HEAD + hg] = *(f16x8*)&CT(m, hg);
        *(f16x8*)&kb[(size_t)(m0 + m) * HEAD + hg] = *(f16x8*)&CT(m, 64 + hg);
        int h = t >> 2, mg = (t & 3) * 8;
        f16x8 vvv;
        #pragma unroll
        for (int jj = 0; jj < 8; jj++)
            ((u16*)&vvv)[jj] = CT(mg + jj, 128 + h);
        int bbt = m0 >> 12, l0 = m0 & 4095;
        *(f16x8*)&vTb[(size_t)(bbt * HEAD + h) * L_SEQ + l0 + mg] = vvv;
    }
#undef WLX
#undef XLX
#undef CT
}

// --- Kernel 2: split-KV causal attention. Uniform 512-kv chunks (<=8 stages),
// single-buffered async staging, 34 KB LDS -> 4 blocks/CU, exp2 softmax.
__global__ __launch_bounds__(256, 4) void attn_chunk(
    const u16* __restrict__ qb, const u16* __restrict__ kb,
    const u16* __restrict__ vT, float* __restrict__ Opart, float* __restrict__ lpart)
{
    const int qt = blockIdx.x, ch = blockIdx.y, b = blockIdx.z;
    if (ch * KCH > qt * 128 + 127) return;

    __shared__ __align__(16) u16 Kls[2 * 64 * 32];   // 8 KB  [dh][64][32]
    __shared__ __align__(16) u16 Vls[2 * 64 * 32];   // 8 KB  [kh][64][32]
    __shared__ __align__(16) u16 Pls[4 * 32 * 72];   // 18 KB wave-private P
#define KBX(dh,r,c) Kls[((dh)*64 + (r))*32 + (c)]
#define VBX(kh,r,c) Vls[((kh)*64 + (r))*32 + (c)]
#define PX(r,c)     Pls[((wv)*32 + (r))*72 + (c)]

    const int t = threadIdx.x, wv = t >> 6, lane = t & 63;
    const int ln16 = lane & 15, quad = lane >> 4;
    const int qmin = qt * 128 + wv * 32;

    // Q as B-operand: B[k=d=quad*8+j][n=q=ln16]; q pre-scaled log2e/8 via Wq
    f16x8 qf[2][2];
    #pragma unroll
    for (int qn = 0; qn < 2; qn++) {
        const u16* qrp = qb + (size_t)(b * L_SEQ + qmin + qn * 16 + ln16) * HEAD + quad * 8;
        qf[qn][0] = ld8h(qrp); qf[qn][1] = ld8h(qrp + 32);
    }

    const u16* kbb = kb + (size_t)b * L_SEQ * HEAD;
    const u16* vbb = vT + (size_t)b * HEAD * L_SEQ;

    f32x4 o[2][4] = {};            // O^T[h=hg*16+quad*4+r][q=qn*16+ln16]
    float lsum[2] = {0.f, 0.f};

    const int kv_lo = ch * KCH;
    const int kv_hi = min(kv_lo + KCH, qt * 128 + 128);
    const int nst = (kv_hi - kv_lo) >> 6;

    auto issue_stage = [&](int kv0) {
        #pragma unroll
        for (int k2 = 0; k2 < 4; k2++) {
            int c = wv * 4 + k2;
            if (c < 8) {
                int dh = c & 1, g = c >> 1;
                const u16* gp = kbb + (size_t)(kv0 + g * 16 + (lane >> 2)) * HEAD
                                    + dh * 32 + (lane & 3) * 8;
                gload16(gp, &KBX(dh, g * 16 + (lane >> 2), (lane & 3) * 8));
            } else {
                int c2 = c - 8, kh = c2 & 1, g = c2 >> 1;
                const u16* gp = vbb + (size_t)(g * 16 + (lane >> 2)) * L_SEQ
                                    + kv0 + kh * 32 + (lane & 3) * 8;
                gload16(gp, &VBX(kh, g * 16 + (lane >> 2), (lane & 3) * 8));
            }
        }
    };

    for (int s = 0; s < nst; s++) {
        const int kv0 = kv_lo + s * 64;
        issue_stage(kv0);
        __syncthreads();               // drain staging

        #pragma unroll
        for (int g = 0; g < 4; g++) {
            f16x8 ka0 = ld8h(&KBX(0, g * 16 + ln16, quad * 8));
            f16x8 ka1 = ld8h(&KBX(1, g * 16 + ln16, quad * 8));
            #pragma unroll
            for (int qn = 0; qn < 2; qn++) {
                f32x4 s2 = {};
                s2 = mfma16h(ka0, qf[qn][0], s2);
                s2 = mfma16h(ka1, qf[qn][1], s2);
                // S^T[kv=kv0+g*16+quad*4+r][q=qmin+qn*16+ln16]; p = 2^s
                float p0, p1, p2, p3;
                if (kv0 + g * 16 + 15 <= qmin + qn * 16) {     // fully unmasked
                    p0 = __builtin_amdgcn_exp2f(s2[0]);
                    p1 = __builtin_amdgcn_exp2f(s2[1]);
                    p2 = __builtin_amdgcn_exp2f(s2[2]);
                    p3 = __builtin_amdgcn_exp2f(s2[3]);
                } else {
                    int q = qmin + qn * 16 + ln16;
                    int kv = kv0 + g * 16 + quad * 4;
                    p0 = (kv     <= q) ? __builtin_amdgcn_exp2f(s2[0]) : 0.f;
                    p1 = (kv + 1 <= q) ? __builtin_amdgcn_exp2f(s2[1]) : 0.f;
                    p2 = (kv + 2 <= q) ? __builtin_amdgcn_exp2f(s2[2]) : 0.f;
                    p3 = (kv + 3 <= q) ? __builtin_amdgcn_exp2f(s2[3]) : 0.f;
                }
                lsum[qn] += (p0 + p1) + (p2 + p3);
                uint2 pk; pk.x = pk16(p0, p1); pk.y = pk16(p2, p3);
                *(uint2*)&PX(qn * 16 + ln16, g * 16 + quad * 4) = pk;
            }
        }
        // P back as B-operand (same-wave LDS, ordered)
        f16x8 pf[2][2];
        #pragma unroll
        for (int qn = 0; qn < 2; qn++) {
            pf[qn][0] = ld8h(&PX(qn * 16 + ln16, quad * 8));
            pf[qn][1] = ld8h(&PX(qn * 16 + ln16, 32 + quad * 8));
        }
        #pragma unroll
        for (int hg = 0; hg < 4; hg++) {
            f16x8 va0 = ld8h(&VBX(0, hg * 16 + ln16, quad * 8));
            f16x8 va1 = ld8h(&VBX(1, hg * 16 + ln16, quad * 8));
            #pragma unroll
            for (int qn = 0; qn < 2; qn++) {
                o[qn][hg] = mfma16h(va0, pf[qn][0], o[qn][hg]);
                o[qn][hg] = mfma16h(va1, pf[qn][1], o[qn][hg]);
            }
        }
        __syncthreads();               // LDS reads done before next overwrite
    }

    #pragma unroll
    for (int qn = 0; qn < 2; qn++) {
        lsum[qn] += __shfl_xor(lsum[qn], 16);
        lsum[qn] += __shfl_xor(lsum[qn], 32);
    }

    const size_t base = (size_t)(b * 144 + Sq(qt) + ch);
    #pragma unroll
    for (int qn = 0; qn < 2; qn++) {
        int q_local = wv * 32 + qn * 16 + ln16;
        #pragma unroll
        for (int hg = 0; hg < 4; hg++)
            *(f32x4*)&Opart[base * 8192 + (size_t)q_local * 64 + hg * 16 + quad * 4] = o[qn][hg];
        if (quad == 0)
            lpart[base * 128 + q_local] = lsum[qn];
    }
#undef KBX
#undef VBX
#undef PX
}

// --- Kernel 3: merge partials; <=8 chunks, scalar-branch-guarded loads.
__global__ __launch_bounds__(256) void merge_chunks(
    const float* __restrict__ Opart, const float* __restrict__ lpart,
    float* __restrict__ out)
{
    const int qt = blockIdx.x, qseg = blockIdx.y, b = blockIdx.z;
    const int nch = (qt + 4) >> 2;      // ceil((qt+1)/4)
    const int t = threadIdx.x;
    const size_t obase = (size_t)(b * 144 + Sq(qt)) * 8192;
    const size_t lbase = (size_t)(b * 144 + Sq(qt)) * 128;
    #pragma unroll
    for (int i = 0; i < 2; i++) {
        int idx = i * 256 + t;              // 32 q x 16 h-groups
        int q = qseg * 32 + (idx >> 4), hg = (idx & 15) * 4;
        float L = 0.f, ax = 0.f, ay = 0.f, az = 0.f, aw = 0.f;
        #pragma unroll
        for (int c = 0; c < MAXCH; c++) {
            if (c < nch) {                  // block-uniform scalar branch
                L += lpart[lbase + c * 128 + q];
                const float4 v = *(const float4*)&Opart[obase + (size_t)c * 8192 + q * 64 + hg];
                ax += v.x; ay += v.y; az += v.z; aw += v.w;
            }
        }
        float inv = 1.f / L;
        float4 r; r.x = ax * inv; r.y = ay * inv; r.z = az * inv; r.w = aw * inv;
        *(float4*)&out[((size_t)(b * L_SEQ + qt * 128 + q)) * HEAD + hg] = r;
    }
}

extern "C" void kernel_launch(void* const* d_in, const int* in_sizes, int n_in,
                              void* d_out, int out_size, void* d_ws, size_t ws_size,
                              hipStream_t stream) {
    const float* x  = (const float*)d_in[0];
    const float* Wq = (const float*)d_in[1];
    const float* Wk = (const float*)d_in[2];
    const float* Wv = (const float*)d_in[3];
    float* out = (float*)d_out;

    u16* ws16 = (u16*)d_ws;
    u16* Wt  = ws16;                          // [192][1024] f16 (q|k|v rows)
    u16* qb  = Wt + 3 * HEAD * D_MODEL;       // [4,4096,64] f16
    u16* kb  = qb + 16384 * HEAD;
    u16* vTb = kb + 16384 * HEAD;             // [4,64,4096] f16
    float* Opart = (float*)(vTb + 16384 * HEAD);   // [4*144][8192] f32 = 18.9 MB
    float* lpart = Opart + (size_t)4 * 144 * 8192; // [4*144][128] f32

    conv_w      <<<dim3(16, 3), 256, 0, stream>>>(Wq, Wk, Wv, Wt);
    qkv_proj    <<<dim3(512), 256, 0, stream>>>(x, Wt, qb, kb, vTb);
    attn_chunk  <<<dim3(NQT, MAXCH, 4), 256, 0, stream>>>(qb, kb, vTb, Opart, lpart);
    merge_chunks<<<dim3(NQT, 4, 4), 256, 0, stream>>>(Opart, lpart, out);
}